// Round 7
// baseline (373.138 us; speedup 1.0000x reference)
//
#include <hip/hip_runtime.h>

#define NROWS   262144
#define NCODES  1024
#define DIM     64
#define LIST_CAP 65536u
#define STEPS   16       // 1024 codes / 64 per step
#define TILES   4        // 16-code MFMA tiles per step
#define RSTRIDE 144      // LDS bytes per code row in main staging
#define BUFB    (TILES * 16 * RSTRIDE)   // 9216 B per buffer
#define BIG     256.0f   // score bias: makes all packed scores positive floats

typedef _Float16 half8 __attribute__((ext_vector_type(8)));
typedef __attribute__((ext_vector_type(4))) float f32x4;

#define MFMA16(acc, a, b) acc = __builtin_amdgcn_mfma_f32_16x16x32_f16(a, b, acc, 0, 0, 0)

__device__ __forceinline__ unsigned umin32(unsigned a, unsigned b) { return a < b ? a : b; }
__device__ __forceinline__ unsigned umax32(unsigned a, unsigned b) { return a > b ? a : b; }

// ---------------------------------------------------------------------------
// Prep: unchanged from r6 (proven absmax 0.0). 4 blocks x 256, thread = row.
// ctrl[0] = max ||c - fp16(c)||^2 bits (atomicMax), ctrl[1] = flag counter.
// ---------------------------------------------------------------------------
__global__ __launch_bounds__(256) void vq_prep(const float* __restrict__ cb,
                                               float* __restrict__ hcsq,
                                               _Float16* __restrict__ Ch,
                                               unsigned* ctrl) {
    const int k = blockIdx.x * 256 + threadIdx.x;   // 0..1023
    const float4* row = (const float4*)(cb + (size_t)k * DIM);
    _Float16* co = Ch + (size_t)k * DIM;
    float s = 0.f, r2 = 0.f;
#pragma unroll
    for (int i = 0; i < 8; ++i) {
        float4 a = row[2 * i], b = row[2 * i + 1];
        float v[8] = {a.x, a.y, a.z, a.w, b.x, b.y, b.z, b.w};
        union { half8 f; _Float16 e[8]; } uh;
#pragma unroll
        for (int j = 0; j < 8; ++j) {
            float c = v[j];
            s += c * c;
            _Float16 h = (_Float16)c;
            uh.e[j] = h;
            float d = c - (float)h;
            r2 += d * d;
        }
        *(half8*)(co + i * 8) = uh.f;
    }
    hcsq[k] = 0.5f * s;
    float w = r2;
#pragma unroll
    for (int off = 1; off < 64; off <<= 1) w = fmaxf(w, __shfl_xor(w, off));
    if ((threadIdx.x & 63) == 0) atomicMax(ctrl + 0, __float_as_uint(w));
}

// ---------------------------------------------------------------------------
// Main: fp16 2-term scores (r6 structure), NEW packed-u32 top-2 epilogue:
// biased score (+BIG-hc folded into acc init) is a positive float -> u32
// order == float order; low 10 mantissa bits replaced by (1023-code) so a
// single u32 max tracks score+index with first-occurrence tie-break. Margin
// gains a rigorous truncation-quantum term t1*2^-12. Near-ties rescued.
// ---------------------------------------------------------------------------
__global__ __launch_bounds__(256) void vq_main(const float* __restrict__ inputs,
                                               const float* __restrict__ cb,
                                               const float* __restrict__ hcsq,
                                               const _Float16* __restrict__ Ch,
                                               const unsigned* ctrl,
                                               float* __restrict__ out,
                                               unsigned* cnt,
                                               unsigned* __restrict__ list) {
    __shared__ __align__(16) char lds[2 * BUFB];
    __shared__ float shc[NCODES];
    const int tid = threadIdx.x;
    const int lane = tid & 63;
    const int wave = tid >> 6;
    const int m = lane & 15;   // A row-in-tile / B code-in-tile / D col
    const int q = lane >> 4;   // k-quad
    const size_t rowbase = (size_t)blockIdx.x * 128 + (size_t)wave * 32;

    for (int i = tid; i < NCODES; i += 256) shc[i] = hcsq[i];

    const float E = sqrtf(__uint_as_float(ctrl[0])) * 1.001f;

    // A fragments (fp16 hi+lo of x) + exact row sum-of-squares for the margin.
    half8 xh[2][2], xl[2][2];
    float xsq[2];
#pragma unroll
    for (int t = 0; t < 2; ++t) {
        const float* px = inputs + (rowbase + t * 16 + m) * DIM;
        float acc = 0.f;
#pragma unroll
        for (int s = 0; s < 2; ++s) {
            const float4* p = (const float4*)(px + q * 8 + s * 32);
            float4 v0 = p[0], v1 = p[1];
            float v[8] = {v0.x, v0.y, v0.z, v0.w, v1.x, v1.y, v1.z, v1.w};
            union { half8 f; _Float16 e[8]; } uh, ul;
#pragma unroll
            for (int j = 0; j < 8; ++j) {
                acc += v[j] * v[j];
                _Float16 h = (_Float16)v[j];
                uh.e[j] = h;
                ul.e[j] = (_Float16)(v[j] - (float)h);
            }
            xh[t][s] = uh.f;
            xl[t][s] = ul.f;
        }
        acc += __shfl_xor(acc, 16);   // reduce across k-quads (same m)
        acc += __shfl_xor(acc, 32);
        xsq[t] = acc;
    }

    unsigned u1[2][4], u2[2][4];   // packed top-2 per (m-tile, r)
#pragma unroll
    for (int t = 0; t < 2; ++t)
#pragma unroll
        for (int r = 0; r < 4; ++r) { u1[t][r] = 0u; u2[t][r] = 0u; }

    // Staging: 512 x 16B segments per step; thread handles seg tid and tid+256.
    const int off0 = ((tid >> 3) * RSTRIDE) + (tid & 7) * 16;            // rows 0..31
    const int off1 = (((tid + 256) >> 3) * RSTRIDE) + (tid & 7) * 16;    // rows 32..63
    char* buf0 = lds;
    char* buf1 = lds + BUFB;
    const uint4* gb = (const uint4*)Ch;   // 16B units; 512 per step

    {   // preload step 0
        uint4 a = gb[tid], b = gb[tid + 256];
        *(uint4*)(buf0 + off0) = a;
        *(uint4*)(buf0 + off1) = b;
    }
    __syncthreads();

    for (int step = 0; step < STEPS; ++step) {
        char* curb = (step & 1) ? buf1 : buf0;
        char* nxtb = (step & 1) ? buf0 : buf1;
        uint4 nv0, nv1;
        const bool more = (step + 1) < STEPS;
        if (more) {
            nv0 = gb[(step + 1) * 512 + tid];
            nv1 = gb[(step + 1) * 512 + tid + 256];
        }
#pragma unroll
        for (int t = 0; t < TILES; ++t) {
            const char* rb = curb + (t * 16 + m) * RSTRIDE + q * 16;
            half8 b0 = *(const half8*)(rb);        // k-step 0 fragment
            half8 b1 = *(const half8*)(rb + 64);   // k-step 1 fragment
            float binit = BIG - shc[step * 64 + t * 16 + m];
            f32x4 a0 = {binit, binit, binit, binit};
            f32x4 a1 = a0;
            MFMA16(a0, xh[0][0], b0); MFMA16(a1, xh[1][0], b0);
            MFMA16(a0, xh[0][1], b1); MFMA16(a1, xh[1][1], b1);
            MFMA16(a0, xl[0][0], b0); MFMA16(a1, xl[1][0], b0);
            MFMA16(a0, xl[0][1], b1); MFMA16(a1, xl[1][1], b1);
            unsigned inv = (unsigned)(1023 - (step * 64 + t * 16) - m);
#pragma unroll
            for (int r = 0; r < 4; ++r) {
                unsigned v0 = (__float_as_uint(a0[r]) & 0xFFFFFC00u) | inv;
                u2[0][r] = umax32(u2[0][r], umin32(u1[0][r], v0));
                u1[0][r] = umax32(u1[0][r], v0);
                unsigned v1 = (__float_as_uint(a1[r]) & 0xFFFFFC00u) | inv;
                u2[1][r] = umax32(u2[1][r], umin32(u1[1][r], v1));
                u1[1][r] = umax32(u1[1][r], v1);
            }
        }
        if (more) {
            *(uint4*)(nxtb + off0) = nv0;
            *(uint4*)(nxtb + off1) = nv1;
        }
        __syncthreads();
    }

    // Cross-lane packed top-2 merge (16-lane groups); unpack, gather, write,
    // flag near-ties with margin incl. truncation quantum.
#pragma unroll
    for (int t = 0; t < 2; ++t)
#pragma unroll
        for (int r = 0; r < 4; ++r) {
            unsigned a = u1[t][r], b2 = u2[t][r];
#pragma unroll
            for (int off = 1; off < 16; off <<= 1) {
                unsigned oa = (unsigned)__shfl_xor((int)a, off);
                unsigned ob = (unsigned)__shfl_xor((int)b2, off);
                b2 = umax32(umax32(b2, ob), umin32(a, oa));
                a = umax32(a, oa);
            }
            int bi = 1023 - (int)(a & 1023u);
            float t1 = __uint_as_float(a & 0xFFFFFC00u);
            float t2 = __uint_as_float(b2 & 0xFFFFFC00u);
            size_t row = rowbase + t * 16 + q * 4 + r;
            float xs = __shfl(xsq[t], (lane & 48) | (q * 4 + r));
            float marg = 2.0f * (sqrtf(xs) * E + 1e-3f) + t1 * 2.4414e-4f;
            const float4* src = (const float4*)(cb + (size_t)bi * DIM);
            ((float4*)(out + row * DIM))[m] = src[m];
            if (m == 0 && (t1 - t2) < marg) {
                unsigned pos = atomicAdd(cnt, 1u);
                if (pos < LIST_CAP) list[pos] = (unsigned)row;
            }
        }
}

// ---------------------------------------------------------------------------
// Rescue v3: exact fp32 re-solve, NO shuffles, conflict-free LDS codebook.
// Block = 256 thr = 32 rows x 8 splits. Codebook tiled 128 codes in LDS with
// 68-float row stride; split c = k0 + sp + 8*jj -> concurrent lanes hit
// distinct bank-quads (4*(sp+j) mod 32), same-sp lanes broadcast.
// Scoring arithmetic identical to r1 (absmax-0 proven).
// ---------------------------------------------------------------------------
#define RROWS 32
#define RTILE 128
#define RPAD  68     // floats per code row in LDS (64 + 4 pad)

__global__ __launch_bounds__(256) void vq_rescue(const float* __restrict__ inputs,
                                                 const float* __restrict__ cb,
                                                 const float* __restrict__ hcsq,
                                                 const unsigned* cnt,
                                                 const unsigned* __restrict__ list,
                                                 float* __restrict__ out) {
    __shared__ __align__(16) float tile[RTILE * RPAD];   // 34816 B
    __shared__ float bsc[RROWS][8];
    __shared__ int   bid[RROWS][8];
    __shared__ int   win[RROWS];
    unsigned n = *cnt;
    if (n > LIST_CAP) n = LIST_CAP;
    unsigned batches = (n + RROWS - 1) / RROWS;
    const int tid = threadIdx.x;
    const int rs = tid >> 3;    // row slot 0..31
    const int sp = tid & 7;     // code split 0..7

    for (unsigned batch = blockIdx.x; batch < batches; batch += gridDim.x) {
        unsigned rowi = batch * RROWS + rs;
        bool valid = rowi < n;
        unsigned row = valid ? list[rowi] : 0u;
        float4 x[16];
        if (valid) {
            const float4* xr = (const float4*)(inputs + (size_t)row * DIM);
#pragma unroll
            for (int j = 0; j < 16; ++j) x[j] = xr[j];
        }
        float best = -INFINITY;
        int bi = 0;
        for (int k0 = 0; k0 < NCODES; k0 += RTILE) {
            __syncthreads();   // protect previous tile / merge arrays
            const float4* src = (const float4*)(cb + (size_t)k0 * DIM);
#pragma unroll
            for (int i = 0; i < (RTILE * 16) / 256; ++i) {   // 8 coalesced f4
                int idx = tid + i * 256;
                *(float4*)(tile + (idx >> 4) * RPAD + (idx & 15) * 4) = src[idx];
            }
            __syncthreads();
            if (valid) {
#pragma unroll 2
                for (int jj = 0; jj < 16; ++jj) {
                    int cl = sp + 8 * jj;
                    int c = k0 + cl;
                    const float4* crow = (const float4*)(tile + cl * RPAD);
                    float s0 = -hcsq[c], s1 = 0.f, s2 = 0.f, s3 = 0.f;
#pragma unroll
                    for (int j = 0; j < 16; ++j) {
                        float4 cv = crow[j];
                        s0 += x[j].x * cv.x;
                        s1 += x[j].y * cv.y;
                        s2 += x[j].z * cv.z;
                        s3 += x[j].w * cv.w;
                    }
                    float s = (s0 + s1) + (s2 + s3);
                    if (s > best) { best = s; bi = c; }   // c increasing/thread
                }
            }
        }
        bsc[rs][sp] = best;
        bid[rs][sp] = bi;
        __syncthreads();
        if (sp == 0 && valid) {
            float b = bsc[rs][0];
            int w = bid[rs][0];
#pragma unroll
            for (int k = 1; k < 8; ++k) {
                float ob = bsc[rs][k];
                int oi = bid[rs][k];
                if (ob > b || (ob == b && oi < w)) { b = ob; w = oi; }
            }
            win[rs] = w;
        }
        __syncthreads();
        if (valid) {
            int wb = win[rs];
            const float4* s4 = (const float4*)(cb + (size_t)wb * DIM);
            float4* d4 = (float4*)(out + (size_t)row * DIM);
#pragma unroll
            for (int w = sp; w < 16; w += 8) d4[w] = s4[w];
        }
    }
}

extern "C" void kernel_launch(void* const* d_in, const int* in_sizes, int n_in,
                              void* d_out, int out_size, void* d_ws, size_t ws_size,
                              hipStream_t stream) {
    const float* inputs = (const float*)d_in[0];    // [262144, 64] fp32
    const float* cb = (const float*)d_in[1];        // [1024, 64] fp32
    float* out = (float*)d_out;

    // ws: hcsq f32[1024] | Ch fp16[65536] | ctrl u32[64] | list u32[65536]
    char* ws = (char*)d_ws;
    float* hcsq = (float*)ws;                                   //   4 KiB
    _Float16* Ch = (_Float16*)(ws + 4096);                      // 128 KiB
    unsigned* ctrl = (unsigned*)(ws + 4096 + 131072);           // 256 B slot
    unsigned* list = (unsigned*)(ws + 4096 + 131072 + 256);     // 256 KiB

    hipMemsetAsync(ctrl, 0, 8, stream);     // E2max, cnt
    vq_prep<<<4, 256, 0, stream>>>(cb, hcsq, Ch, ctrl);
    vq_main<<<NROWS / 128, 256, 0, stream>>>(inputs, cb, hcsq, Ch, ctrl,
                                             out, ctrl + 1, list);
    vq_rescue<<<512, 256, 0, stream>>>(inputs, cb, hcsq, ctrl + 1, list, out);
}